// Round 1
// baseline (1047.491 us; speedup 1.0000x reference)
//
#include <hip/hip_runtime.h>
#include <math.h>

#define B_  16
#define C_  512
#define HW_ 3136
#define K_  128            // WCH
#define CHW (C_ * HW_)     // 1605632

// ---------------- pooled[b,c] = mean_n y[b,c,n] ----------------
__global__ __launch_bounds__(256) void k_pool(const float* __restrict__ y,
                                              float* __restrict__ pooled) {
    int bc = blockIdx.x;
    const float* yp = y + (long)bc * HW_;
    float acc = 0.f;
    for (int n = threadIdx.x; n < HW_; n += 256) acc += yp[n];
    __shared__ float red[256];
    red[threadIdx.x] = acc;
    __syncthreads();
    for (int s = 128; s > 0; s >>= 1) {
        if (threadIdx.x < s) red[threadIdx.x] += red[threadIdx.x + s];
        __syncthreads();
    }
    if (threadIdx.x == 0) pooled[bc] = red[0] * (1.0f / HW_);
}

// ---------------- rou_y[b,k] = sigmoid(pooled[b,:] . rou_w[k,:] + rou_b[k]) ----------------
__global__ __launch_bounds__(128) void k_rou(const float* __restrict__ pooled,
                                             const float* __restrict__ rou_w,
                                             const float* __restrict__ rou_b,
                                             float* __restrict__ rou_y) {
    int b = blockIdx.x;
    int k = threadIdx.x;
    __shared__ float ps[C_];
    for (int c = threadIdx.x; c < C_; c += 128) ps[c] = pooled[b * C_ + c];
    __syncthreads();
    float acc = rou_b[k];
    for (int c = 0; c < C_; ++c) acc += ps[c] * rou_w[k * C_ + c];
    rou_y[b * K_ + k] = 1.0f / (1.0f + expf(-acc));
}

// ---------------- phi_x[b,n,k] = relu(sum_c phi_w[k,c]*x[b,c,n] + phi_b[k]) ----------------
// tile: 64n x 64k, K=C_ in chunks of 32. LDS reduction-major [q][row].
__global__ __launch_bounds__(256) void k_phi(const float* __restrict__ x,
                                             const float* __restrict__ phi_w,
                                             const float* __restrict__ phi_b,
                                             float* __restrict__ phi_x) {
    int b  = blockIdx.z;
    int k0 = blockIdx.y * 64;
    int n0 = blockIdx.x * 64;
    __shared__ float At[32][68];   // [c-chunk][k]
    __shared__ float Bt[32][68];   // [c-chunk][n]
    int t = threadIdx.x;
    int tk = t & 15, tn = t >> 4;
    float acc[4][4] = {};          // [k][n]
    const float* xb = x + b * CHW;
    for (int p0 = 0; p0 < C_; p0 += 32) {
        #pragma unroll
        for (int j = 0; j < 8; ++j) {
            int idx = t + j * 256;
            int kk = idx >> 5, q = idx & 31;
            At[q][kk] = phi_w[(k0 + kk) * C_ + p0 + q];
        }
        #pragma unroll
        for (int j = 0; j < 8; ++j) {
            int idx = t + j * 256;
            int q = idx >> 6, nn = idx & 63;
            Bt[q][nn] = xb[(p0 + q) * HW_ + n0 + nn];
        }
        __syncthreads();
        #pragma unroll
        for (int q = 0; q < 32; ++q) {
            float4 a  = *reinterpret_cast<const float4*>(&At[q][tk * 4]);
            float4 bb = *reinterpret_cast<const float4*>(&Bt[q][tn * 4]);
            float av[4] = {a.x, a.y, a.z, a.w};
            float bv[4] = {bb.x, bb.y, bb.z, bb.w};
            #pragma unroll
            for (int i = 0; i < 4; ++i)
                #pragma unroll
                for (int j = 0; j < 4; ++j) acc[i][j] += av[i] * bv[j];
        }
        __syncthreads();
    }
    #pragma unroll
    for (int j = 0; j < 4; ++j) {
        int n = n0 + tn * 4 + j;
        float4 o;
        o.x = fmaxf(acc[0][j] + phi_b[k0 + tk * 4 + 0], 0.f);
        o.y = fmaxf(acc[1][j] + phi_b[k0 + tk * 4 + 1], 0.f);
        o.z = fmaxf(acc[2][j] + phi_b[k0 + tk * 4 + 2], 0.f);
        o.w = fmaxf(acc[3][j] + phi_b[k0 + tk * 4 + 3], 0.f);
        *reinterpret_cast<float4*>(&phi_x[(b * HW_ + n) * K_ + k0 + tk * 4]) = o;
    }
}

// ---------------- s[b,k] += sum_{n in chunk} phi_x[b,n,k] ----------------
__global__ __launch_bounds__(128) void k_s(const float* __restrict__ phi_x,
                                           float* __restrict__ s) {
    int b = blockIdx.y;
    int n0 = blockIdx.x * 64;
    int k = threadIdx.x;
    const float* p = phi_x + (b * HW_ + n0) * K_ + k;
    float acc = 0.f;
    for (int i = 0; i < 64; ++i) acc += p[i * K_];
    atomicAdd(&s[b * K_ + k], acc);
}

// ---------------- inv_sqrt[b,n] = rsqrt(sum_k phi_x[b,n,k]*rou_y[b,k]*s[b,k] + 1e-8) ----------------
__global__ __launch_bounds__(256) void k_d(const float* __restrict__ phi_x,
                                           const float* __restrict__ rou_y,
                                           const float* __restrict__ s,
                                           float* __restrict__ inv_sqrt) {
    int b = blockIdx.y;
    __shared__ float w_s[K_];
    int t = threadIdx.x;
    if (t < K_) w_s[t] = rou_y[b * K_ + t] * s[b * K_ + t];
    __syncthreads();
    int wave = t >> 6, lane = t & 63;
    int n = blockIdx.x * 4 + wave;
    const float* p = phi_x + (b * HW_ + n) * K_;
    float v = p[lane] * w_s[lane] + p[lane + 64] * w_s[lane + 64];
    #pragma unroll
    for (int off = 32; off > 0; off >>= 1) v += __shfl_down(v, off, 64);
    if (lane == 0) inv_sqrt[b * HW_ + n] = rsqrtf(v + 1e-8f);
}

// ---------------- t[b,k,c] = sum_n (phi_x[b,n,k]*inv_sqrt[b,n]) * x_trans[b,n,c] ----------------
// x_trans[b,n,c] = x[b*CHW + n*C_ + c] (raw reshape). tile 64k x 64c, K=HW_ chunks 32.
__global__ __launch_bounds__(256) void k_t(const float* __restrict__ phi_x,
                                           const float* __restrict__ inv_sqrt,
                                           const float* __restrict__ x,
                                           float* __restrict__ tmat) {
    int b  = blockIdx.z;
    int k0 = blockIdx.y * 64;
    int c0 = blockIdx.x * 64;
    __shared__ float At[32][68];   // [n-chunk][k]
    __shared__ float Bt[32][68];   // [n-chunk][c]
    int t = threadIdx.x;
    int tk = t & 15, tc = t >> 4;
    float acc[4][4] = {};
    const float* pb = phi_x + b * HW_ * K_;
    const float* xb = x + b * CHW;
    const float* ib = inv_sqrt + b * HW_;
    for (int nb = 0; nb < HW_; nb += 32) {
        #pragma unroll
        for (int j = 0; j < 8; ++j) {
            int idx = t + j * 256;
            int ni = idx >> 6, kk = idx & 63;
            At[ni][kk] = pb[(nb + ni) * K_ + k0 + kk] * ib[nb + ni];
        }
        #pragma unroll
        for (int j = 0; j < 8; ++j) {
            int idx = t + j * 256;
            int ni = idx >> 6, cc = idx & 63;
            Bt[ni][cc] = xb[(nb + ni) * C_ + c0 + cc];
        }
        __syncthreads();
        #pragma unroll
        for (int q = 0; q < 32; ++q) {
            float4 a  = *reinterpret_cast<const float4*>(&At[q][tk * 4]);
            float4 bb = *reinterpret_cast<const float4*>(&Bt[q][tc * 4]);
            float av[4] = {a.x, a.y, a.z, a.w};
            float bv[4] = {bb.x, bb.y, bb.z, bb.w};
            #pragma unroll
            for (int i = 0; i < 4; ++i)
                #pragma unroll
                for (int j = 0; j < 4; ++j) acc[i][j] += av[i] * bv[j];
        }
        __syncthreads();
    }
    float* tb = tmat + b * K_ * C_;
    #pragma unroll
    for (int i = 0; i < 4; ++i) {
        float4 o = {acc[i][0], acc[i][1], acc[i][2], acc[i][3]};
        *reinterpret_cast<float4*>(&tb[(k0 + tk * 4 + i) * C_ + c0 + tc * 4]) = o;
    }
}

// ---------------- tz[b,k,c] = rou_y[b,k] * sum_{c'} t[b,k,c'] * zeta_w[c,c'] ----------------
__global__ __launch_bounds__(256) void k_tz(const float* __restrict__ tmat,
                                            const float* __restrict__ zeta_w,
                                            const float* __restrict__ rou_y,
                                            float* __restrict__ tz) {
    int b  = blockIdx.z;
    int k0 = blockIdx.y * 64;
    int c0 = blockIdx.x * 64;
    __shared__ float At[32][68];   // [c'][k]
    __shared__ float Bt[32][68];   // [c'][c]
    int t = threadIdx.x;
    int tk = t & 15, tc = t >> 4;
    float acc[4][4] = {};
    const float* tb = tmat + b * K_ * C_;
    for (int p0 = 0; p0 < C_; p0 += 32) {
        #pragma unroll
        for (int j = 0; j < 8; ++j) {
            int idx = t + j * 256;
            int kk = idx >> 5, q = idx & 31;
            At[q][kk] = tb[(k0 + kk) * C_ + p0 + q];
        }
        #pragma unroll
        for (int j = 0; j < 8; ++j) {
            int idx = t + j * 256;
            int cc = idx >> 5, q = idx & 31;
            Bt[q][cc] = zeta_w[(c0 + cc) * C_ + p0 + q];
        }
        __syncthreads();
        #pragma unroll
        for (int q = 0; q < 32; ++q) {
            float4 a  = *reinterpret_cast<const float4*>(&At[q][tk * 4]);
            float4 bb = *reinterpret_cast<const float4*>(&Bt[q][tc * 4]);
            float av[4] = {a.x, a.y, a.z, a.w};
            float bv[4] = {bb.x, bb.y, bb.z, bb.w};
            #pragma unroll
            for (int i = 0; i < 4; ++i)
                #pragma unroll
                for (int j = 0; j < 4; ++j) acc[i][j] += av[i] * bv[j];
        }
        __syncthreads();
    }
    float* tzb = tz + b * K_ * C_;
    #pragma unroll
    for (int i = 0; i < 4; ++i) {
        float r = rou_y[b * K_ + k0 + tk * 4 + i];
        float4 o = {r * acc[i][0], r * acc[i][1], r * acc[i][2], r * acc[i][3]};
        *reinterpret_cast<float4*>(&tzb[(k0 + tk * 4 + i) * C_ + c0 + tc * 4]) = o;
    }
}

// ---------------- out[b, n*C+c] = x_flat + relu( x_trans@zeta^T - P@tz + zeta_b ) ----------------
__global__ __launch_bounds__(256) void k_out(const float* __restrict__ x,
                                             const float* __restrict__ zeta_w,
                                             const float* __restrict__ zeta_b,
                                             const float* __restrict__ phi_x,
                                             const float* __restrict__ inv_sqrt,
                                             const float* __restrict__ tz,
                                             float* __restrict__ out) {
    int b  = blockIdx.z;
    int n0 = blockIdx.y * 64;
    int c0 = blockIdx.x * 64;
    __shared__ float At[32][68];
    __shared__ float Bt[32][68];
    int t = threadIdx.x;
    int tn = t & 15, tc = t >> 4;
    float acc[4][4] = {};          // [n][c]
    const float* xb = x + b * CHW;
    // phase 1: + x_trans @ zeta^T   (K = C_)
    for (int p0 = 0; p0 < C_; p0 += 32) {
        #pragma unroll
        for (int j = 0; j < 8; ++j) {
            int idx = t + j * 256;
            int nn = idx >> 5, q = idx & 31;
            At[q][nn] = xb[(n0 + nn) * C_ + p0 + q];
        }
        #pragma unroll
        for (int j = 0; j < 8; ++j) {
            int idx = t + j * 256;
            int cc = idx >> 5, q = idx & 31;
            Bt[q][cc] = zeta_w[(c0 + cc) * C_ + p0 + q];
        }
        __syncthreads();
        #pragma unroll
        for (int q = 0; q < 32; ++q) {
            float4 a  = *reinterpret_cast<const float4*>(&At[q][tn * 4]);
            float4 bb = *reinterpret_cast<const float4*>(&Bt[q][tc * 4]);
            float av[4] = {a.x, a.y, a.z, a.w};
            float bv[4] = {bb.x, bb.y, bb.z, bb.w};
            #pragma unroll
            for (int i = 0; i < 4; ++i)
                #pragma unroll
                for (int j = 0; j < 4; ++j) acc[i][j] += av[i] * bv[j];
        }
        __syncthreads();
    }
    // phase 2: - P @ tz   (K = K_)
    const float* pb  = phi_x + b * HW_ * K_;
    const float* ib  = inv_sqrt + b * HW_;
    const float* tzb = tz + b * K_ * C_;
    for (int p0 = 0; p0 < K_; p0 += 32) {
        #pragma unroll
        for (int j = 0; j < 8; ++j) {
            int idx = t + j * 256;
            int nn = idx >> 5, q = idx & 31;
            At[q][nn] = pb[(n0 + nn) * K_ + p0 + q] * ib[n0 + nn];
        }
        #pragma unroll
        for (int j = 0; j < 8; ++j) {
            int idx = t + j * 256;
            int q = idx >> 6, cc = idx & 63;
            Bt[q][cc] = tzb[(p0 + q) * C_ + c0 + cc];
        }
        __syncthreads();
        #pragma unroll
        for (int q = 0; q < 32; ++q) {
            float4 a  = *reinterpret_cast<const float4*>(&At[q][tn * 4]);
            float4 bb = *reinterpret_cast<const float4*>(&Bt[q][tc * 4]);
            float av[4] = {a.x, a.y, a.z, a.w};
            float bv[4] = {bb.x, bb.y, bb.z, bb.w};
            #pragma unroll
            for (int i = 0; i < 4; ++i)
                #pragma unroll
                for (int j = 0; j < 4; ++j) acc[i][j] -= av[i] * bv[j];
        }
        __syncthreads();
    }
    // epilogue: + zeta_b, relu, + x residual (same flat layout), store
    #pragma unroll
    for (int i = 0; i < 4; ++i) {
        int n = n0 + tn * 4 + i;
        const float4 xr = *reinterpret_cast<const float4*>(&xb[n * C_ + c0 + tc * 4]);
        float4 o;
        o.x = xr.x + fmaxf(acc[i][0] + zeta_b[c0 + tc * 4 + 0], 0.f);
        o.y = xr.y + fmaxf(acc[i][1] + zeta_b[c0 + tc * 4 + 1], 0.f);
        o.z = xr.z + fmaxf(acc[i][2] + zeta_b[c0 + tc * 4 + 2], 0.f);
        o.w = xr.w + fmaxf(acc[i][3] + zeta_b[c0 + tc * 4 + 3], 0.f);
        *reinterpret_cast<float4*>(&out[b * CHW + n * C_ + c0 + tc * 4]) = o;
    }
}

extern "C" void kernel_launch(void* const* d_in, const int* in_sizes, int n_in,
                              void* d_out, int out_size, void* d_ws, size_t ws_size,
                              hipStream_t stream) {
    const float* x      = (const float*)d_in[0];
    const float* y      = (const float*)d_in[1];
    const float* phi_w  = (const float*)d_in[2];
    const float* phi_b  = (const float*)d_in[3];
    const float* rou_w  = (const float*)d_in[4];
    const float* rou_b  = (const float*)d_in[5];
    const float* zeta_w = (const float*)d_in[6];
    const float* zeta_b = (const float*)d_in[7];
    float* out = (float*)d_out;
    float* ws  = (float*)d_ws;

    float* phi_x  = ws;                                   // B*HW*K  = 6,422,528
    float* tmat   = phi_x  + (size_t)B_ * HW_ * K_;       // B*K*C   = 1,048,576
    float* tzbuf  = tmat   + (size_t)B_ * K_ * C_;        // B*K*C   = 1,048,576
    float* pooled = tzbuf  + (size_t)B_ * K_ * C_;        // B*C     = 8192
    float* rou_y  = pooled + B_ * C_;                     // B*K     = 2048
    float* sbuf   = rou_y  + B_ * K_;                     // B*K     = 2048
    float* inv_s  = sbuf   + B_ * K_;                     // B*HW    = 50176
    // total ~8.58M floats = 34.3 MB of d_ws

    hipMemsetAsync(sbuf, 0, B_ * K_ * sizeof(float), stream);

    k_pool<<<B_ * C_, 256, 0, stream>>>(y, pooled);
    k_rou <<<B_, 128, 0, stream>>>(pooled, rou_w, rou_b, rou_y);
    k_phi <<<dim3(HW_ / 64, K_ / 64, B_), 256, 0, stream>>>(x, phi_w, phi_b, phi_x);
    k_s   <<<dim3(HW_ / 64, B_), 128, 0, stream>>>(phi_x, sbuf);
    k_d   <<<dim3(HW_ / 4, B_), 256, 0, stream>>>(phi_x, rou_y, sbuf, inv_s);
    k_t   <<<dim3(C_ / 64, K_ / 64, B_), 256, 0, stream>>>(phi_x, inv_s, x, tmat);
    k_tz  <<<dim3(C_ / 64, K_ / 64, B_), 256, 0, stream>>>(tmat, zeta_w, rou_y, tzbuf);
    k_out <<<dim3(C_ / 64, HW_ / 64, B_), 256, 0, stream>>>(x, zeta_w, zeta_b, phi_x, inv_s, tzbuf, out);
}

// Round 2
// 582.386 us; speedup vs baseline: 1.7986x; 1.7986x over previous
//
#include <hip/hip_runtime.h>
#include <math.h>

#define B_  16
#define C_  512
#define HW_ 3136
#define K_  128
#define CHW (C_ * HW_)

typedef __bf16 bf16x8_t __attribute__((ext_vector_type(8)));
typedef __bf16 bf16x4_t __attribute__((ext_vector_type(4)));
typedef __bf16 bf16x2_t __attribute__((ext_vector_type(2)));
typedef float floatx4  __attribute__((ext_vector_type(4)));

typedef const __attribute__((address_space(1))) void* gas_ptr;
typedef __attribute__((address_space(3))) void*       las_ptr;

// ---- stage a 128x32 bf16 tile (rows x k) into LDS with XOR-swizzled 16B slots ----
// LDS element (m, slot) holds global k-group k8 = slot ^ ((m>>1)&3); rows clamped.
__device__ __forceinline__ void stage128x32(const __bf16* __restrict__ base, long ld,
                                            int row0, int rowmax, int k0,
                                            __bf16* lds, int t) {
    int w = t >> 6;
    #pragma unroll
    for (int i = 0; i < 2; ++i) {
        int u = i * 256 + t;            // 16-byte unit index, 512 total
        int m = u >> 2;
        int slot = u & 3;
        int k8 = slot ^ ((m >> 1) & 3);
        int r = row0 + m; if (r > rowmax) r = rowmax;
        const __bf16* g = base + (long)r * ld + (k0 + k8 * 8);
        __bf16* l = lds + (size_t)(i * 256 + w * 64) * 8;   // wave-uniform base
        __builtin_amdgcn_global_load_lds((gas_ptr)g, (las_ptr)l, 16, 0, 0);
    }
}

// ---- one BK=32 step: 8 ds_read_b128 + 16 mfma per wave ----
__device__ __forceinline__ void mma_step(const __bf16* As, const __bf16* Bs,
                                         floatx4 acc[4][4], int abase, int bbase) {
    bf16x8_t af[4], bf[4];
    #pragma unroll
    for (int i = 0; i < 4; ++i)
        af[i] = *(const bf16x8_t*)((const char*)As + abase + i * 1024);
    #pragma unroll
    for (int i = 0; i < 4; ++i)
        bf[i] = *(const bf16x8_t*)((const char*)Bs + bbase + i * 1024);
    #pragma unroll
    for (int mi = 0; mi < 4; ++mi)
        #pragma unroll
        for (int ni = 0; ni < 4; ++ni)
            acc[mi][ni] = __builtin_amdgcn_mfma_f32_16x16x32_bf16(af[mi], bf[ni], acc[mi][ni], 0, 0, 0);
}

// ================= small / prep kernels =================

__global__ __launch_bounds__(256) void k_pool(const float* __restrict__ y,
                                              float* __restrict__ pooled) {
    int bc = blockIdx.x;
    const float* yp = y + (long)bc * HW_;
    float acc = 0.f;
    for (int n = threadIdx.x; n < HW_; n += 256) acc += yp[n];
    __shared__ float red[256];
    red[threadIdx.x] = acc;
    __syncthreads();
    for (int s = 128; s > 0; s >>= 1) {
        if (threadIdx.x < s) red[threadIdx.x] += red[threadIdx.x + s];
        __syncthreads();
    }
    if (threadIdx.x == 0) pooled[bc] = red[0] * (1.0f / HW_);
}

__global__ __launch_bounds__(128) void k_rou(const float* __restrict__ pooled,
                                             const float* __restrict__ rou_w,
                                             const float* __restrict__ rou_b,
                                             float* __restrict__ rou_y) {
    int b = blockIdx.x;
    int k = threadIdx.x;
    __shared__ float ps[C_];
    for (int c = threadIdx.x; c < C_; c += 128) ps[c] = pooled[b * C_ + c];
    __syncthreads();
    float acc = rou_b[k];
    for (int c = 0; c < C_; ++c) acc += ps[c] * rou_w[k * C_ + c];
    rou_y[b * K_ + k] = 1.0f / (1.0f + expf(-acc));
}

// flat bf16 cast, n divisible by 2048, one thread per 8 elems
__global__ __launch_bounds__(256) void k_cast8(const float* __restrict__ a,
                                               __bf16* __restrict__ o) {
    long i = ((long)blockIdx.x * 256 + threadIdx.x) * 8;
    float4 v0 = *reinterpret_cast<const float4*>(a + i);
    float4 v1 = *reinterpret_cast<const float4*>(a + i + 4);
    bf16x8_t r;
    r[0] = (__bf16)v0.x; r[1] = (__bf16)v0.y; r[2] = (__bf16)v0.z; r[3] = (__bf16)v0.w;
    r[4] = (__bf16)v1.x; r[5] = (__bf16)v1.y; r[6] = (__bf16)v1.z; r[7] = (__bf16)v1.w;
    *reinterpret_cast<bf16x8_t*>(o + i) = r;
}

// x1t[b][n][c] = bf16(x[b][c][n])   (conv-view transpose)
__global__ __launch_bounds__(256) void k_tr1(const float* __restrict__ xf,
                                             __bf16* __restrict__ x1t) {
    int b = blockIdx.z, c0 = blockIdx.y * 64, n0 = blockIdx.x * 64;
    __shared__ float ld[64][65];
    int t = threadIdx.x, tn = t & 63, g = t >> 6;
    const float* xb = xf + (long)b * CHW;
    #pragma unroll 4
    for (int r = 0; r < 16; ++r) {
        int c = c0 + g * 16 + r;
        ld[g * 16 + r][tn] = xb[(long)c * HW_ + n0 + tn];
    }
    __syncthreads();
    __bf16* ob = x1t + (long)b * CHW;
    #pragma unroll 4
    for (int r = 0; r < 16; ++r) {
        int n = n0 + g * 16 + r;
        ob[(long)n * C_ + c0 + tn] = (__bf16)ld[tn][g * 16 + r];
    }
}

// x2s[b][c][n] = bf16(xf[b][n*C+c] * inv_s[b][n])  (reshape-view transpose, scaled)
__global__ __launch_bounds__(256) void k_tr2s(const float* __restrict__ xf,
                                              const float* __restrict__ inv_s,
                                              __bf16* __restrict__ x2s) {
    int b = blockIdx.z, c0 = blockIdx.y * 64, n0 = blockIdx.x * 64;
    __shared__ float ld[64][65];
    int t = threadIdx.x, tc = t & 63, g = t >> 6;
    const float* xb = xf + (long)b * CHW;
    #pragma unroll 4
    for (int r = 0; r < 16; ++r) {
        int n = n0 + g * 16 + r;
        ld[g * 16 + r][tc] = xb[(long)n * C_ + c0 + tc] * inv_s[b * HW_ + n];
    }
    __syncthreads();
    __bf16* ob = x2s + (long)b * CHW;
    #pragma unroll 4
    for (int r = 0; r < 16; ++r) {
        int c = c0 + g * 16 + r;
        ob[(long)c * HW_ + n0 + tc] = (__bf16)ld[tc][g * 16 + r];
    }
}

// ================= MFMA GEMMs =================

// phi (relu(phi_w @ X1 + b)) -> phi_kn[k][n] and phi_nk[n][k]
__global__ __launch_bounds__(256) void k_phi_m(const __bf16* __restrict__ x1t,
                                               const __bf16* __restrict__ pwbf,
                                               const float* __restrict__ phi_b,
                                               __bf16* __restrict__ phi_kn,
                                               __bf16* __restrict__ phi_nk) {
    int b = blockIdx.y;
    int n0 = blockIdx.x * 128;
    __shared__ __bf16 As[4096];
    __shared__ __bf16 Bs[4096];
    int t = threadIdx.x, w = t >> 6, lane = t & 63;
    int lm = lane & 15, q = lane >> 4;
    int wrow = w >> 1, wcol = w & 1;
    floatx4 acc[4][4];
    #pragma unroll
    for (int i = 0; i < 4; ++i)
        #pragma unroll
        for (int j = 0; j < 4; ++j) acc[i][j] = (floatx4){0.f, 0.f, 0.f, 0.f};

    const __bf16* Bb = x1t + (long)b * CHW;
    int soff = ((q ^ ((lm >> 1) & 3)) << 4);
    int abase = (wrow * 64 + lm) * 64 + soff;
    int bbase = (wcol * 64 + lm) * 64 + soff;

    for (int p0 = 0; p0 < C_; p0 += 32) {
        stage128x32(pwbf, C_, 0, K_ - 1, p0, As, t);
        stage128x32(Bb,   C_, n0, HW_ - 1, p0, Bs, t);
        __syncthreads();
        mma_step(As, Bs, acc, abase, bbase);
        __syncthreads();
    }
    #pragma unroll
    for (int mi = 0; mi < 4; ++mi) {
        int kb = wrow * 64 + mi * 16 + q * 4;
        float4 pb = *reinterpret_cast<const float4*>(phi_b + kb);
        float pbv[4] = {pb.x, pb.y, pb.z, pb.w};
        #pragma unroll
        for (int ni = 0; ni < 4; ++ni) {
            int n = n0 + wcol * 64 + ni * 16 + lm;
            if (n < HW_) {
                bf16x4_t pack;
                #pragma unroll
                for (int r = 0; r < 4; ++r) {
                    float v = fmaxf(acc[mi][ni][r] + pbv[r], 0.f);
                    __bf16 vb = (__bf16)v;
                    phi_kn[((long)b * K_ + kb + r) * HW_ + n] = vb;
                    pack[r] = vb;
                }
                *reinterpret_cast<bf16x4_t*>(phi_nk + ((long)b * HW_ + n) * K_ + kb) = pack;
            }
        }
    }
}

// s[b][k] = sum_n phi_kn[b][k][n]
__global__ __launch_bounds__(64) void k_s2(const __bf16* __restrict__ phi_kn,
                                           float* __restrict__ s) {
    int bk = blockIdx.x;
    const __bf16* p = phi_kn + (long)bk * HW_;
    float a = 0.f;
    for (int n = threadIdx.x; n < HW_; n += 64) a += (float)p[n];
    #pragma unroll
    for (int off = 32; off > 0; off >>= 1) a += __shfl_down(a, off, 64);
    if (threadIdx.x == 0) s[bk] = a;
}

// fused: D[n] -> inv_s[n]; scale phi_nk row in place -> P_nk
__global__ __launch_bounds__(256) void k_d2(__bf16* __restrict__ phi_nk,
                                            const float* __restrict__ rou_y,
                                            const float* __restrict__ s,
                                            float* __restrict__ inv_s) {
    int b = blockIdx.y;
    __shared__ float ws[K_];
    int t = threadIdx.x;
    if (t < K_) ws[t] = rou_y[b * K_ + t] * s[b * K_ + t];
    __syncthreads();
    int w = t >> 6, lane = t & 63;
    int n = blockIdx.x * 4 + w;
    __bf16* p = phi_nk + ((long)b * HW_ + n) * K_ + lane * 2;
    bf16x2_t v = *reinterpret_cast<bf16x2_t*>(p);
    float f0 = (float)v[0], f1 = (float)v[1];
    float d = f0 * ws[lane * 2] + f1 * ws[lane * 2 + 1];
    #pragma unroll
    for (int off = 32; off > 0; off >>= 1) d += __shfl_xor(d, off, 64);
    float inv = rsqrtf(d + 1e-8f);
    bf16x2_t o; o[0] = (__bf16)(f0 * inv); o[1] = (__bf16)(f1 * inv);
    *reinterpret_cast<bf16x2_t*>(p) = o;
    if (lane == 0) inv_s[b * HW_ + n] = inv;
}

// t[k][c] += sum_{n chunk} phi_kn[k][n] * x2s[c][n]   (split-K over 7 chunks, fp32 atomics)
__global__ __launch_bounds__(256) void k_t_m(const __bf16* __restrict__ phi_kn,
                                             const __bf16* __restrict__ x2s,
                                             float* __restrict__ t_f32) {
    int b = blockIdx.z;
    int c0 = blockIdx.x * 128;
    int nch = blockIdx.y;
    __shared__ __bf16 As[4096];
    __shared__ __bf16 Bs[4096];
    int t = threadIdx.x, w = t >> 6, lane = t & 63;
    int lm = lane & 15, q = lane >> 4;
    int wrow = w >> 1, wcol = w & 1;
    floatx4 acc[4][4];
    #pragma unroll
    for (int i = 0; i < 4; ++i)
        #pragma unroll
        for (int j = 0; j < 4; ++j) acc[i][j] = (floatx4){0.f, 0.f, 0.f, 0.f};

    const __bf16* Ab = phi_kn + (long)b * K_ * HW_;
    const __bf16* Bb = x2s + (long)b * CHW;
    int soff = ((q ^ ((lm >> 1) & 3)) << 4);
    int abase = (wrow * 64 + lm) * 64 + soff;
    int bbase = (wcol * 64 + lm) * 64 + soff;

    int pstart = nch * 448;
    for (int p0 = pstart; p0 < pstart + 448; p0 += 32) {
        stage128x32(Ab, HW_, 0, K_ - 1, p0, As, t);
        stage128x32(Bb, HW_, c0, C_ - 1, p0, Bs, t);
        __syncthreads();
        mma_step(As, Bs, acc, abase, bbase);
        __syncthreads();
    }
    #pragma unroll
    for (int mi = 0; mi < 4; ++mi) {
        int kb = wrow * 64 + mi * 16 + q * 4;
        #pragma unroll
        for (int ni = 0; ni < 4; ++ni) {
            int c = c0 + wcol * 64 + ni * 16 + lm;
            #pragma unroll
            for (int r = 0; r < 4; ++r)
                atomicAdd(&t_f32[((long)b * K_ + kb + r) * C_ + c], acc[mi][ni][r]);
        }
    }
}

// tzT[c][k] = -rou[k] * sum_{c'} t[k][c'] * zeta_w[c][c']   (fp32 VALU, small)
__global__ __launch_bounds__(256) void k_tz2(const float* __restrict__ tmat,
                                             const float* __restrict__ zeta_w,
                                             const float* __restrict__ rou_y,
                                             __bf16* __restrict__ tzT) {
    int b = blockIdx.z;
    int k0 = blockIdx.y * 64;
    int c0 = blockIdx.x * 64;
    __shared__ float At[32][68];
    __shared__ float Bt[32][68];
    int t = threadIdx.x;
    int tk = t & 15, tc = t >> 4;
    float acc[4][4] = {};
    const float* tb = tmat + (long)b * K_ * C_;
    for (int p0 = 0; p0 < C_; p0 += 32) {
        #pragma unroll
        for (int j = 0; j < 8; ++j) {
            int idx = t + j * 256;
            int kk = idx >> 5, q = idx & 31;
            At[q][kk] = tb[(k0 + kk) * C_ + p0 + q];
        }
        #pragma unroll
        for (int j = 0; j < 8; ++j) {
            int idx = t + j * 256;
            int cc = idx >> 5, q = idx & 31;
            Bt[q][cc] = zeta_w[(long)(c0 + cc) * C_ + p0 + q];
        }
        __syncthreads();
        #pragma unroll
        for (int q = 0; q < 32; ++q) {
            float4 a  = *reinterpret_cast<const float4*>(&At[q][tk * 4]);
            float4 bb = *reinterpret_cast<const float4*>(&Bt[q][tc * 4]);
            float av[4] = {a.x, a.y, a.z, a.w};
            float bv[4] = {bb.x, bb.y, bb.z, bb.w};
            #pragma unroll
            for (int i = 0; i < 4; ++i)
                #pragma unroll
                for (int j = 0; j < 4; ++j) acc[i][j] += av[i] * bv[j];
        }
        __syncthreads();
    }
    #pragma unroll
    for (int i = 0; i < 4; ++i) {
        int k = k0 + tk * 4 + i;
        float r = rou_y[b * K_ + k];
        #pragma unroll
        for (int j = 0; j < 4; ++j) {
            int c = c0 + tc * 4 + j;
            tzT[((long)b * C_ + c) * K_ + k] = (__bf16)(-r * acc[i][j]);
        }
    }
}

// out[n][c] = xf + relu( X2@zeta^T + P_nk@tzT^T + zeta_b )
__global__ __launch_bounds__(256) void k_out_m(const __bf16* __restrict__ xbf2,
                                               const __bf16* __restrict__ zwbf,
                                               const __bf16* __restrict__ pnk,
                                               const __bf16* __restrict__ tzT,
                                               const float* __restrict__ xf,
                                               const float* __restrict__ zeta_b,
                                               float* __restrict__ out) {
    int b = blockIdx.z;
    int n0 = blockIdx.y * 128;
    int c0 = blockIdx.x * 128;
    __shared__ __bf16 As[4096];
    __shared__ __bf16 Bs[4096];
    int t = threadIdx.x, w = t >> 6, lane = t & 63;
    int lm = lane & 15, q = lane >> 4;
    int wrow = w >> 1, wcol = w & 1;
    floatx4 acc[4][4];
    #pragma unroll
    for (int i = 0; i < 4; ++i)
        #pragma unroll
        for (int j = 0; j < 4; ++j) acc[i][j] = (floatx4){0.f, 0.f, 0.f, 0.f};

    int soff = ((q ^ ((lm >> 1) & 3)) << 4);
    int abase = (wrow * 64 + lm) * 64 + soff;
    int bbase = (wcol * 64 + lm) * 64 + soff;

    // phase 1: X2 @ zeta^T  (red = 512)
    const __bf16* A1 = xbf2 + (long)b * CHW;
    for (int p0 = 0; p0 < C_; p0 += 32) {
        stage128x32(A1,   C_, n0, HW_ - 1, p0, As, t);
        stage128x32(zwbf, C_, c0, C_ - 1, p0, Bs, t);
        __syncthreads();
        mma_step(As, Bs, acc, abase, bbase);
        __syncthreads();
    }
    // phase 2: P_nk @ tzT^T  (red = 128, tzT pre-negated & rou-folded)
    const __bf16* A2 = pnk + (long)b * (long)HW_ * K_;
    const __bf16* B2 = tzT + (long)b * (long)C_ * K_;
    for (int p0 = 0; p0 < K_; p0 += 32) {
        stage128x32(A2, K_, n0, HW_ - 1, p0, As, t);
        stage128x32(B2, K_, c0, C_ - 1, p0, Bs, t);
        __syncthreads();
        mma_step(As, Bs, acc, abase, bbase);
        __syncthreads();
    }
    // epilogue
    #pragma unroll
    for (int mi = 0; mi < 4; ++mi) {
        int nb = n0 + wrow * 64 + mi * 16 + q * 4;
        #pragma unroll
        for (int ni = 0; ni < 4; ++ni) {
            int c = c0 + wcol * 64 + ni * 16 + lm;
            float zb = zeta_b[c];
            #pragma unroll
            for (int r = 0; r < 4; ++r) {
                int n = nb + r;
                if (n < HW_) {
                    long idx = (long)b * CHW + (long)n * C_ + c;
                    out[idx] = xf[idx] + fmaxf(acc[mi][ni][r] + zb, 0.f);
                }
            }
        }
    }
}

extern "C" void kernel_launch(void* const* d_in, const int* in_sizes, int n_in,
                              void* d_out, int out_size, void* d_ws, size_t ws_size,
                              hipStream_t stream) {
    const float* x      = (const float*)d_in[0];
    const float* y      = (const float*)d_in[1];
    const float* phi_w  = (const float*)d_in[2];
    const float* phi_b  = (const float*)d_in[3];
    const float* rou_w  = (const float*)d_in[4];
    const float* rou_b  = (const float*)d_in[5];
    const float* zeta_w = (const float*)d_in[6];
    const float* zeta_b = (const float*)d_in[7];
    float* out = (float*)d_out;

    char* p = (char*)d_ws;
    __bf16* xbf2   = (__bf16*)p; p += (size_t)B_ * CHW * 2;          // 51.4 MB
    __bf16* x1t    = (__bf16*)p; p += (size_t)B_ * CHW * 2;          // 51.4 MB (reused as x2s)
    __bf16* phi_kn = (__bf16*)p; p += (size_t)B_ * K_ * HW_ * 2;     // 12.85 MB
    __bf16* phi_nk = (__bf16*)p; p += (size_t)B_ * K_ * HW_ * 2;     // 12.85 MB (becomes P_nk)
    float*  t_f32  = (float*) p; p += (size_t)B_ * K_ * C_ * 4;      // 4.2 MB
    __bf16* tzT    = (__bf16*)p; p += (size_t)B_ * C_ * K_ * 2;      // 2.1 MB
    __bf16* pwbf   = (__bf16*)p; p += (size_t)K_ * C_ * 2;
    __bf16* zwbf   = (__bf16*)p; p += (size_t)C_ * C_ * 2;
    float*  pooled = (float*) p; p += (size_t)B_ * C_ * 4;
    float*  rou_y  = (float*) p; p += (size_t)B_ * K_ * 4;
    float*  sbuf   = (float*) p; p += (size_t)B_ * K_ * 4;
    float*  inv_s  = (float*) p; p += (size_t)B_ * HW_ * 4;
    __bf16* x2s    = x1t;  // x1t dead after k_phi_m

    hipMemsetAsync(t_f32, 0, (size_t)B_ * K_ * C_ * 4, stream);

    k_pool <<<B_ * C_, 256, 0, stream>>>(y, pooled);
    k_rou  <<<B_, 128, 0, stream>>>(pooled, rou_w, rou_b, rou_y);
    k_cast8<<<(B_ * (long)CHW) / 2048, 256, 0, stream>>>(x, xbf2);
    k_cast8<<<(K_ * C_) / 2048, 256, 0, stream>>>(phi_w, pwbf);
    k_cast8<<<(C_ * C_) / 2048, 256, 0, stream>>>(zeta_w, zwbf);
    k_tr1  <<<dim3(HW_ / 64, C_ / 64, B_), 256, 0, stream>>>(x, x1t);
    k_phi_m<<<dim3(25, B_), 256, 0, stream>>>(x1t, pwbf, phi_b, phi_kn, phi_nk);
    k_s2   <<<B_ * K_, 64, 0, stream>>>(phi_kn, sbuf);
    k_d2   <<<dim3(HW_ / 4, B_), 256, 0, stream>>>(phi_nk, rou_y, sbuf, inv_s);
    k_tr2s <<<dim3(HW_ / 64, C_ / 64, B_), 256, 0, stream>>>(x, inv_s, x2s);
    k_t_m  <<<dim3(C_ / 128, 7, B_), 256, 0, stream>>>(phi_kn, x2s, t_f32);
    k_tz2  <<<dim3(C_ / 64, K_ / 64, B_), 256, 0, stream>>>(t_f32, zeta_w, rou_y, tzT);
    k_out_m<<<dim3(C_ / 128, 25, B_), 256, 0, stream>>>(xbf2, zwbf, phi_nk, tzT, x, zeta_b, out);
}

// Round 3
// 476.282 us; speedup vs baseline: 2.1993x; 1.2228x over previous
//
#include <hip/hip_runtime.h>
#include <math.h>

#define B_  16
#define C_  512
#define HW_ 3136
#define K_  128
#define CHW (C_ * HW_)

typedef __bf16 bf16x8_t __attribute__((ext_vector_type(8)));
typedef __bf16 bf16x4_t __attribute__((ext_vector_type(4)));
typedef __bf16 bf16x2_t __attribute__((ext_vector_type(2)));
typedef float floatx4  __attribute__((ext_vector_type(4)));

typedef const __attribute__((address_space(1))) void* gas_ptr;
typedef __attribute__((address_space(3))) void*       las_ptr;

// ---- stage a 128x64 bf16 tile (rows x k) into LDS, XOR-swizzled 16B units ----
// unit u in [0,1024): m=u>>3, slot=u&7; holds global k-group kg = slot ^ (m&7).
__device__ __forceinline__ void stage128x64(const __bf16* __restrict__ base, long ld,
                                            int row0, int rowmax, int k0,
                                            __bf16* lds, int t) {
    int w = t >> 6;
    #pragma unroll
    for (int i = 0; i < 4; ++i) {
        int u = i * 256 + t;
        int m = u >> 3, slot = u & 7;
        int kg = slot ^ (m & 7);
        int r = row0 + m; if (r > rowmax) r = rowmax;
        const __bf16* g = base + (long)r * ld + (k0 + kg * 8);
        __bf16* l = lds + (size_t)(i * 256 + w * 64) * 8;   // wave-uniform base
        __builtin_amdgcn_global_load_lds((gas_ptr)g, (las_ptr)l, 16, 0, 0);
    }
}

// ---- one BK=64 step: 16 ds_read_b128 + 32 mfma per wave ----
__device__ __forceinline__ void mma_step64(const char* As, const char* Bs,
                                           floatx4 acc[4][4], int aoff, int boff,
                                           int q, int lxor) {
    #pragma unroll
    for (int h = 0; h < 2; ++h) {
        int s = (((h * 4 + q) ^ lxor) << 4);
        bf16x8_t af[4], bf[4];
        #pragma unroll
        for (int i = 0; i < 4; ++i)
            af[i] = *(const bf16x8_t*)(As + aoff + i * 2048 + s);
        #pragma unroll
        for (int i = 0; i < 4; ++i)
            bf[i] = *(const bf16x8_t*)(Bs + boff + i * 2048 + s);
        #pragma unroll
        for (int mi = 0; mi < 4; ++mi)
            #pragma unroll
            for (int ni = 0; ni < 4; ++ni)
                acc[mi][ni] = __builtin_amdgcn_mfma_f32_16x16x32_bf16(af[mi], bf[ni], acc[mi][ni], 0, 0, 0);
    }
}

// ================= small / prep kernels =================

__global__ __launch_bounds__(256) void k_pool(const float* __restrict__ y,
                                              float* __restrict__ pooled) {
    int bc = blockIdx.x;
    const float* yp = y + (long)bc * HW_;
    float acc = 0.f;
    for (int n = threadIdx.x; n < HW_; n += 256) acc += yp[n];
    __shared__ float red[256];
    red[threadIdx.x] = acc;
    __syncthreads();
    for (int s = 128; s > 0; s >>= 1) {
        if (threadIdx.x < s) red[threadIdx.x] += red[threadIdx.x + s];
        __syncthreads();
    }
    if (threadIdx.x == 0) pooled[bc] = red[0] * (1.0f / HW_);
}

__global__ __launch_bounds__(128) void k_rou(const float* __restrict__ pooled,
                                             const float* __restrict__ rou_w,
                                             const float* __restrict__ rou_b,
                                             float* __restrict__ rou_y) {
    int b = blockIdx.x;
    int k = threadIdx.x;
    __shared__ float ps[C_];
    for (int c = threadIdx.x; c < C_; c += 128) ps[c] = pooled[b * C_ + c];
    __syncthreads();
    float acc = rou_b[k];
    for (int c = 0; c < C_; ++c) acc += ps[c] * rou_w[k * C_ + c];
    rou_y[b * K_ + k] = 1.0f / (1.0f + expf(-acc));
}

// flat bf16 cast, count divisible by 2048
__global__ __launch_bounds__(256) void k_cast8(const float* __restrict__ a,
                                               __bf16* __restrict__ o) {
    long i = ((long)blockIdx.x * 256 + threadIdx.x) * 8;
    float4 v0 = *reinterpret_cast<const float4*>(a + i);
    float4 v1 = *reinterpret_cast<const float4*>(a + i + 4);
    bf16x8_t r;
    r[0] = (__bf16)v0.x; r[1] = (__bf16)v0.y; r[2] = (__bf16)v0.z; r[3] = (__bf16)v0.w;
    r[4] = (__bf16)v1.x; r[5] = (__bf16)v1.y; r[6] = (__bf16)v1.z; r[7] = (__bf16)v1.w;
    *reinterpret_cast<bf16x8_t*>(o + i) = r;
}

// fused: xbf2 (flat cast) + x1t[n][c] = bf16(x[c][n]) in one x read
__global__ __launch_bounds__(256) void k_prep(const float* __restrict__ xf,
                                              __bf16* __restrict__ xbf2,
                                              __bf16* __restrict__ x1t) {
    int b = blockIdx.z, c0 = blockIdx.y * 64, n0 = blockIdx.x * 64;
    __shared__ float ld[64][65];
    int t = threadIdx.x, tn = t & 63, g = t >> 6;
    const float* xb = xf + (long)b * CHW;
    __bf16* fb = xbf2 + (long)b * CHW;
    #pragma unroll 4
    for (int r = 0; r < 16; ++r) {
        int c = c0 + g * 16 + r;
        float v = xb[(long)c * HW_ + n0 + tn];
        ld[g * 16 + r][tn] = v;
        fb[(long)c * HW_ + n0 + tn] = (__bf16)v;
    }
    __syncthreads();
    __bf16* ob = x1t + (long)b * CHW;
    #pragma unroll 4
    for (int r = 0; r < 16; ++r) {
        int n = n0 + g * 16 + r;
        ob[(long)n * C_ + c0 + tn] = (__bf16)ld[tn][g * 16 + r];
    }
}

// x2s[c][n] = bf16(xbf2[n*C+c] * inv_s[n])
__global__ __launch_bounds__(256) void k_tr2s(const __bf16* __restrict__ xbf2,
                                              const float* __restrict__ inv_s,
                                              __bf16* __restrict__ x2s) {
    int b = blockIdx.z, c0 = blockIdx.y * 64, n0 = blockIdx.x * 64;
    __shared__ float ld[64][65];
    int t = threadIdx.x, tc = t & 63, g = t >> 6;
    const __bf16* xb = xbf2 + (long)b * CHW;
    #pragma unroll 4
    for (int r = 0; r < 16; ++r) {
        int n = n0 + g * 16 + r;
        ld[g * 16 + r][tc] = (float)xb[(long)n * C_ + c0 + tc] * inv_s[b * HW_ + n];
    }
    __syncthreads();
    __bf16* ob = x2s + (long)b * CHW;
    #pragma unroll 4
    for (int r = 0; r < 16; ++r) {
        int c = c0 + g * 16 + r;
        ob[(long)c * HW_ + n0 + tc] = (__bf16)ld[tc][g * 16 + r];
    }
}

// ================= MFMA GEMMs =================

// phi: relu(phi_w @ X1 + b) -> phi_kn[k][n], phi_nk[n][k]; fused s[k] column sums
__global__ __launch_bounds__(256) void k_phi_m(const __bf16* __restrict__ x1t,
                                               const __bf16* __restrict__ pwbf,
                                               const float* __restrict__ phi_b,
                                               __bf16* __restrict__ phi_kn,
                                               __bf16* __restrict__ phi_nk,
                                               float* __restrict__ sbuf) {
    int b = blockIdx.y;
    int n0 = blockIdx.x * 128;
    __shared__ __bf16 As[8192];
    __shared__ __bf16 Bs[8192];
    int t = threadIdx.x, w = t >> 6, lane = t & 63;
    int lm = lane & 15, q = lane >> 4;
    int wrow = w >> 1, wcol = w & 1;
    floatx4 acc[4][4];
    #pragma unroll
    for (int i = 0; i < 4; ++i)
        #pragma unroll
        for (int j = 0; j < 4; ++j) acc[i][j] = (floatx4){0.f, 0.f, 0.f, 0.f};

    const __bf16* Bb = x1t + (long)b * CHW;
    int lxor = lm & 7;
    int aoff = (wrow * 64 + lm) * 128;
    int boff = (wcol * 64 + lm) * 128;

    for (int p0 = 0; p0 < C_; p0 += 64) {
        stage128x64(pwbf, C_, 0, K_ - 1, p0, As, t);
        stage128x64(Bb,   C_, n0, HW_ - 1, p0, Bs, t);
        __syncthreads();
        mma_step64((const char*)As, (const char*)Bs, acc, aoff, boff, q, lxor);
        __syncthreads();
    }
    #pragma unroll
    for (int mi = 0; mi < 4; ++mi) {
        int kb = wrow * 64 + mi * 16 + q * 4;
        float4 pb = *reinterpret_cast<const float4*>(phi_b + kb);
        float pbv[4] = {pb.x, pb.y, pb.z, pb.w};
        float sv[4] = {0.f, 0.f, 0.f, 0.f};
        #pragma unroll
        for (int ni = 0; ni < 4; ++ni) {
            int n = n0 + wcol * 64 + ni * 16 + lm;
            if (n < HW_) {
                bf16x4_t pack;
                #pragma unroll
                for (int r = 0; r < 4; ++r) {
                    float v = fmaxf(acc[mi][ni][r] + pbv[r], 0.f);
                    __bf16 vb = (__bf16)v;
                    phi_kn[((long)b * K_ + kb + r) * HW_ + n] = vb;
                    pack[r] = vb;
                    sv[r] += v;
                }
                *reinterpret_cast<bf16x4_t*>(phi_nk + ((long)b * HW_ + n) * K_ + kb) = pack;
            }
        }
        #pragma unroll
        for (int r = 0; r < 4; ++r) {
            float v = sv[r];
            v += __shfl_xor(v, 1, 64); v += __shfl_xor(v, 2, 64);
            v += __shfl_xor(v, 4, 64); v += __shfl_xor(v, 8, 64);
            if (lm == 0) atomicAdd(&sbuf[b * K_ + kb + r], v);
        }
    }
}

// fused: D[n] -> inv_s[n]; scale phi_nk row in place -> P_nk
__global__ __launch_bounds__(256) void k_d2(__bf16* __restrict__ phi_nk,
                                            const float* __restrict__ rou_y,
                                            const float* __restrict__ s,
                                            float* __restrict__ inv_s) {
    int b = blockIdx.y;
    __shared__ float ws[K_];
    int t = threadIdx.x;
    if (t < K_) ws[t] = rou_y[b * K_ + t] * s[b * K_ + t];
    __syncthreads();
    int w = t >> 6, lane = t & 63;
    int n = blockIdx.x * 4 + w;
    __bf16* p = phi_nk + ((long)b * HW_ + n) * K_ + lane * 2;
    bf16x2_t v = *reinterpret_cast<bf16x2_t*>(p);
    float f0 = (float)v[0], f1 = (float)v[1];
    float d = f0 * ws[lane * 2] + f1 * ws[lane * 2 + 1];
    #pragma unroll
    for (int off = 32; off > 0; off >>= 1) d += __shfl_xor(d, off, 64);
    float inv = rsqrtf(d + 1e-8f);
    bf16x2_t o; o[0] = (__bf16)(f0 * inv); o[1] = (__bf16)(f1 * inv);
    *reinterpret_cast<bf16x2_t*>(p) = o;
    if (lane == 0) inv_s[b * HW_ + n] = inv;
}

// t[k][c] += sum_{n chunk} phi_kn[k][n] * x2s[c][n]   (split-K=7, fp32 atomics)
__global__ __launch_bounds__(256) void k_t_m(const __bf16* __restrict__ phi_kn,
                                             const __bf16* __restrict__ x2s,
                                             float* __restrict__ t_f32) {
    int b = blockIdx.z;
    int c0 = blockIdx.x * 128;
    int nch = blockIdx.y;
    __shared__ __bf16 As[8192];
    __shared__ __bf16 Bs[8192];
    int t = threadIdx.x, w = t >> 6, lane = t & 63;
    int lm = lane & 15, q = lane >> 4;
    int wrow = w >> 1, wcol = w & 1;
    floatx4 acc[4][4];
    #pragma unroll
    for (int i = 0; i < 4; ++i)
        #pragma unroll
        for (int j = 0; j < 4; ++j) acc[i][j] = (floatx4){0.f, 0.f, 0.f, 0.f};

    const __bf16* Ab = phi_kn + (long)b * K_ * HW_;
    const __bf16* Bb = x2s + (long)b * CHW;
    int lxor = lm & 7;
    int aoff = (wrow * 64 + lm) * 128;
    int boff = (wcol * 64 + lm) * 128;

    int pstart = nch * 448;
    for (int p0 = pstart; p0 < pstart + 448; p0 += 64) {
        stage128x64(Ab, HW_, 0, K_ - 1, p0, As, t);
        stage128x64(Bb, HW_, c0, C_ - 1, p0, Bs, t);
        __syncthreads();
        mma_step64((const char*)As, (const char*)Bs, acc, aoff, boff, q, lxor);
        __syncthreads();
    }
    #pragma unroll
    for (int mi = 0; mi < 4; ++mi) {
        int kb = wrow * 64 + mi * 16 + q * 4;
        #pragma unroll
        for (int ni = 0; ni < 4; ++ni) {
            int c = c0 + wcol * 64 + ni * 16 + lm;
            #pragma unroll
            for (int r = 0; r < 4; ++r)
                atomicAdd(&t_f32[((long)b * K_ + kb + r) * C_ + c], acc[mi][ni][r]);
        }
    }
}

// tzT[c][k] = -rou[k] * sum_{c'} t_bf[k][c'] * zwbf[c][c']   (MFMA)
__global__ __launch_bounds__(256) void k_tz_m(const __bf16* __restrict__ zwbf,
                                              const __bf16* __restrict__ t_bf,
                                              const float* __restrict__ rou_y,
                                              __bf16* __restrict__ tzT) {
    int b = blockIdx.y;
    int c0 = blockIdx.x * 128;
    __shared__ __bf16 As[8192];
    __shared__ __bf16 Bs[8192];
    int t = threadIdx.x, w = t >> 6, lane = t & 63;
    int lm = lane & 15, q = lane >> 4;
    int wrow = w >> 1, wcol = w & 1;
    floatx4 acc[4][4];
    #pragma unroll
    for (int i = 0; i < 4; ++i)
        #pragma unroll
        for (int j = 0; j < 4; ++j) acc[i][j] = (floatx4){0.f, 0.f, 0.f, 0.f};

    const __bf16* Bb = t_bf + (long)b * K_ * C_;
    int lxor = lm & 7;
    int aoff = (wrow * 64 + lm) * 128;
    int boff = (wcol * 64 + lm) * 128;

    for (int p0 = 0; p0 < C_; p0 += 64) {
        stage128x64(zwbf, C_, c0, C_ - 1, p0, As, t);
        stage128x64(Bb,   C_, 0, K_ - 1, p0, Bs, t);
        __syncthreads();
        mma_step64((const char*)As, (const char*)Bs, acc, aoff, boff, q, lxor);
        __syncthreads();
    }
    #pragma unroll
    for (int mi = 0; mi < 4; ++mi) {
        int c = c0 + wrow * 64 + mi * 16 + q * 4;
        #pragma unroll
        for (int ni = 0; ni < 4; ++ni) {
            int k = wcol * 64 + ni * 16 + lm;
            float rk = rou_y[b * K_ + k];
            #pragma unroll
            for (int r = 0; r < 4; ++r)
                tzT[((long)b * C_ + c + r) * K_ + k] = (__bf16)(-rk * acc[mi][ni][r]);
        }
    }
}

// out[n][c] = bf16(x) + relu( X2@zeta^T + P_nk@tzT^T + zeta_b ), coalesced epilogue
__global__ __launch_bounds__(256) void k_out_m(const __bf16* __restrict__ xbf2,
                                               const __bf16* __restrict__ zwbf,
                                               const __bf16* __restrict__ pnk,
                                               const __bf16* __restrict__ tzT,
                                               const float* __restrict__ zeta_b,
                                               float* __restrict__ out) {
    int b = blockIdx.z;
    int n0 = blockIdx.y * 128;
    int c0 = blockIdx.x * 128;
    __shared__ __attribute__((aligned(16))) char smem[32768];
    __bf16* As = (__bf16*)smem;
    __bf16* Bs = (__bf16*)(smem + 16384);
    int t = threadIdx.x, w = t >> 6, lane = t & 63;
    int lm = lane & 15, q = lane >> 4;
    int wrow = w >> 1, wcol = w & 1;
    floatx4 acc[4][4];
    #pragma unroll
    for (int i = 0; i < 4; ++i)
        #pragma unroll
        for (int j = 0; j < 4; ++j) acc[i][j] = (floatx4){0.f, 0.f, 0.f, 0.f};

    int lxor = lm & 7;
    int aoff = (wrow * 64 + lm) * 128;
    int boff = (wcol * 64 + lm) * 128;

    // phase 1: X2 @ zeta^T  (red = 512)
    const __bf16* A1 = xbf2 + (long)b * CHW;
    for (int p0 = 0; p0 < C_; p0 += 64) {
        stage128x64(A1,   C_, n0, HW_ - 1, p0, As, t);
        stage128x64(zwbf, C_, c0, C_ - 1, p0, Bs, t);
        __syncthreads();
        mma_step64((const char*)As, (const char*)Bs, acc, aoff, boff, q, lxor);
        __syncthreads();
    }
    // phase 2: P_nk @ tzT^T  (red = 128, tzT pre-negated & rou-folded)
    const __bf16* A2 = pnk + (long)b * (long)HW_ * K_;
    const __bf16* B2 = tzT + (long)b * (long)C_ * K_;
    for (int p0 = 0; p0 < K_; p0 += 64) {
        stage128x64(A2, K_, n0, HW_ - 1, p0, As, t);
        stage128x64(B2, K_, c0, C_ - 1, p0, Bs, t);
        __syncthreads();
        mma_step64((const char*)As, (const char*)Bs, acc, aoff, boff, q, lxor);
        __syncthreads();
    }
    // epilogue: bounce through LDS for coalesced dwordx4 stores
    float* ep = (float*)smem;                   // [32][132]
    const __bf16* xres = xbf2 + (long)b * CHW;
    int lr = t >> 3, lc = (t & 7) * 16;
    #pragma unroll
    for (int ch = 0; ch < 4; ++ch) {
        __syncthreads();
        if (wrow == (ch >> 1)) {
            #pragma unroll
            for (int mm = 0; mm < 2; ++mm) {
                int mi = (ch & 1) * 2 + mm;
                #pragma unroll
                for (int ni = 0; ni < 4; ++ni)
                    #pragma unroll
                    for (int r = 0; r < 4; ++r)
                        ep[(mm * 16 + q * 4 + r) * 132 + wcol * 64 + ni * 16 + lm] = acc[mi][ni][r];
            }
        }
        __syncthreads();
        int n = n0 + ch * 32 + lr;
        if (n < HW_) {
            long rowbase = (long)n * C_ + c0 + lc;
            bf16x8_t x0 = *(const bf16x8_t*)(xres + rowbase);
            bf16x8_t x1 = *(const bf16x8_t*)(xres + rowbase + 8);
            float xv[16];
            #pragma unroll
            for (int j = 0; j < 8; ++j) { xv[j] = (float)x0[j]; xv[8 + j] = (float)x1[j]; }
            float* orow = out + (long)b * CHW + rowbase;
            #pragma unroll
            for (int jj = 0; jj < 4; ++jj) {
                float4 zb = *reinterpret_cast<const float4*>(zeta_b + c0 + lc + jj * 4);
                float4 e  = *reinterpret_cast<const float4*>(&ep[lr * 132 + lc + jj * 4]);
                float4 o;
                o.x = xv[jj * 4 + 0] + fmaxf(e.x + zb.x, 0.f);
                o.y = xv[jj * 4 + 1] + fmaxf(e.y + zb.y, 0.f);
                o.z = xv[jj * 4 + 2] + fmaxf(e.z + zb.z, 0.f);
                o.w = xv[jj * 4 + 3] + fmaxf(e.w + zb.w, 0.f);
                *reinterpret_cast<float4*>(orow + jj * 4) = o;
            }
        }
    }
}

extern "C" void kernel_launch(void* const* d_in, const int* in_sizes, int n_in,
                              void* d_out, int out_size, void* d_ws, size_t ws_size,
                              hipStream_t stream) {
    const float* x      = (const float*)d_in[0];
    const float* y      = (const float*)d_in[1];
    const float* phi_w  = (const float*)d_in[2];
    const float* phi_b  = (const float*)d_in[3];
    const float* rou_w  = (const float*)d_in[4];
    const float* rou_b  = (const float*)d_in[5];
    const float* zeta_w = (const float*)d_in[6];
    const float* zeta_b = (const float*)d_in[7];
    float* out = (float*)d_out;

    char* p = (char*)d_ws;
    __bf16* xbf2   = (__bf16*)p; p += (size_t)B_ * CHW * 2;          // 51.4 MB
    __bf16* x1t    = (__bf16*)p; p += (size_t)B_ * CHW * 2;          // 51.4 MB (reused: x2s, then t_bf)
    __bf16* phi_kn = (__bf16*)p; p += (size_t)B_ * K_ * HW_ * 2;     // 12.85 MB
    __bf16* phi_nk = (__bf16*)p; p += (size_t)B_ * K_ * HW_ * 2;     // 12.85 MB (becomes P_nk)
    float*  t_f32  = (float*) p; p += (size_t)B_ * K_ * C_ * 4;      // 4.2 MB
    __bf16* tzT    = (__bf16*)p; p += (size_t)B_ * C_ * K_ * 2;      // 2.1 MB
    __bf16* pwbf   = (__bf16*)p; p += (size_t)K_ * C_ * 2;
    __bf16* zwbf   = (__bf16*)p; p += (size_t)C_ * C_ * 2;
    float*  pooled = (float*) p; p += (size_t)B_ * C_ * 4;
    float*  rou_y  = (float*) p; p += (size_t)B_ * K_ * 4;
    float*  sbuf   = (float*) p; p += (size_t)B_ * K_ * 4;
    float*  inv_s  = (float*) p; p += (size_t)B_ * HW_ * 4;
    __bf16* x2s    = x1t;   // x1t dead after k_phi_m
    __bf16* t_bf   = x1t;   // x2s dead after k_t_m

    hipMemsetAsync(sbuf, 0, B_ * K_ * sizeof(float), stream);
    hipMemsetAsync(t_f32, 0, (size_t)B_ * K_ * C_ * sizeof(float), stream);

    k_pool <<<B_ * C_, 256, 0, stream>>>(y, pooled);
    k_rou  <<<B_, 128, 0, stream>>>(pooled, rou_w, rou_b, rou_y);
    k_cast8<<<(K_ * C_) / 2048, 256, 0, stream>>>(phi_w, pwbf);
    k_cast8<<<(C_ * C_) / 2048, 256, 0, stream>>>(zeta_w, zwbf);
    k_prep <<<dim3(HW_ / 64, C_ / 64, B_), 256, 0, stream>>>(x, xbf2, x1t);
    k_phi_m<<<dim3(25, B_), 256, 0, stream>>>(x1t, pwbf, phi_b, phi_kn, phi_nk, sbuf);
    k_d2   <<<dim3(HW_ / 4, B_), 256, 0, stream>>>(phi_nk, rou_y, sbuf, inv_s);
    k_tr2s <<<dim3(HW_ / 64, C_ / 64, B_), 256, 0, stream>>>(xbf2, inv_s, x2s);
    k_t_m  <<<dim3(C_ / 128, 7, B_), 256, 0, stream>>>(phi_kn, x2s, t_f32);
    k_cast8<<<(B_ * K_ * C_) / 2048, 256, 0, stream>>>(t_f32, t_bf);
    k_tz_m <<<dim3(C_ / 128, B_), 256, 0, stream>>>(zwbf, t_bf, rou_y, tzT);
    k_out_m<<<dim3(C_ / 128, 25, B_), 256, 0, stream>>>(xbf2, zwbf, phi_nk, tzT, zeta_b, out);
}

// Round 4
// 427.997 us; speedup vs baseline: 2.4474x; 1.1128x over previous
//
#include <hip/hip_runtime.h>
#include <math.h>

#define B_  16
#define C_  512
#define HW_ 3136
#define K_  128
#define CHW (C_ * HW_)

typedef __bf16 bf16x8_t __attribute__((ext_vector_type(8)));
typedef __bf16 bf16x4_t __attribute__((ext_vector_type(4)));
typedef __bf16 bf16x2_t __attribute__((ext_vector_type(2)));
typedef float floatx4  __attribute__((ext_vector_type(4)));

typedef const __attribute__((address_space(1))) void* gas_ptr;
typedef __attribute__((address_space(3))) void*       las_ptr;

static __device__ __forceinline__ unsigned short bfbits(__bf16 v) {
    return __builtin_bit_cast(unsigned short, v);
}

// ---- direct staging: 128x64 bf16 tile (rows x red), XOR-swizzled 16B units ----
// unit u: m=u>>3, slot=u&7; holds red-group kg = slot ^ (m&7). Row stride 128 B.
__device__ __forceinline__ void stage128x64(const __bf16* __restrict__ base, long ld,
                                            int row0, int rowmax, int k0,
                                            __bf16* lds, int t) {
    int w = t >> 6;
    #pragma unroll
    for (int i = 0; i < 4; ++i) {
        int u = i * 256 + t;
        int m = u >> 3, slot = u & 7;
        int kg = slot ^ (m & 7);
        int r = row0 + m; if (r > rowmax) r = rowmax;
        const __bf16* g = base + (long)r * ld + (k0 + kg * 8);
        __bf16* l = lds + (size_t)(i * 256 + w * 64) * 8;   // wave-uniform base
        __builtin_amdgcn_global_load_lds((gas_ptr)g, (las_ptr)l, 16, 0, 0);
    }
}

// ---- transposed-staged B tile layout: 128 rows x 64 red, row stride 144 B ----
// element (row, r): byte = row*144 + (((r>>3) + row + (row>>3))&7)*16 + (r&7)*2
// k_phi B: LDS[n][c] from xbf2[c][n]
__device__ __forceinline__ void stage_tr_phi(const __bf16* __restrict__ src,
                                             int n0, int p0, char* Bs, int t) {
    int ng = t & 15;              // rows ng*8 .. ng*8+7
    int cp2 = (t >> 4) * 2;       // even red index in [0,32)
    #pragma unroll
    for (int ci = 0; ci < 2; ++ci) {
        int cc = cp2 + ci * 32;   // even, [0,64)
        const __bf16* g0 = src + (long)(p0 + cc) * HW_ + n0 + ng * 8;
        bf16x8_t v0 = *(const bf16x8_t*)g0;
        bf16x8_t v1 = *(const bf16x8_t*)(g0 + HW_);
        int r8 = cc >> 3, sub = (cc & 7) >> 1;
        #pragma unroll
        for (int j = 0; j < 8; ++j) {
            int row = ng * 8 + j;
            int slot = (r8 + row + (row >> 3)) & 7;
            unsigned int pr = ((unsigned int)bfbits(v1[j]) << 16) | bfbits(v0[j]);
            *(unsigned int*)(Bs + row * 144 + slot * 16 + sub * 4) = pr;
        }
    }
}

// k_t B: LDS[c][n] from xbf2 flat [n][c], scaled by inv_s[n]
__device__ __forceinline__ void stage_tr_t(const __bf16* __restrict__ src,
                                           const float* __restrict__ isrc,
                                           int c0, int p0, char* Bs, int t) {
    int cg = t & 15;
    int np2 = (t >> 4) * 2;
    #pragma unroll
    for (int ni = 0; ni < 2; ++ni) {
        int nn = np2 + ni * 32;
        int n = p0 + nn;                     // always < HW_ (7*448 = 3136)
        float s0 = isrc[n], s1 = isrc[n + 1];
        const __bf16* g0 = src + (long)n * C_ + c0 + cg * 8;
        bf16x8_t v0 = *(const bf16x8_t*)g0;
        bf16x8_t v1 = *(const bf16x8_t*)(g0 + C_);
        int r8 = nn >> 3, sub = (nn & 7) >> 1;
        #pragma unroll
        for (int j = 0; j < 8; ++j) {
            int row = cg * 8 + j;
            int slot = (r8 + row + (row >> 3)) & 7;
            __bf16 a0 = (__bf16)((float)v0[j] * s0);
            __bf16 a1 = (__bf16)((float)v1[j] * s1);
            unsigned int pr = ((unsigned int)bfbits(a1) << 16) | bfbits(a0);
            *(unsigned int*)(Bs + row * 144 + slot * 16 + sub * 4) = pr;
        }
    }
}

// ---- BK=64 step, A direct layout, B direct layout ----
__device__ __forceinline__ void mma_step64(const char* As, const char* Bs,
                                           floatx4 acc[4][4], int aoff, int boff,
                                           int q, int lxor) {
    #pragma unroll
    for (int h = 0; h < 2; ++h) {
        int s = (((h * 4 + q) ^ lxor) << 4);
        bf16x8_t af[4], bf[4];
        #pragma unroll
        for (int i = 0; i < 4; ++i) af[i] = *(const bf16x8_t*)(As + aoff + i * 2048 + s);
        #pragma unroll
        for (int i = 0; i < 4; ++i) bf[i] = *(const bf16x8_t*)(Bs + boff + i * 2048 + s);
        #pragma unroll
        for (int mi = 0; mi < 4; ++mi)
            #pragma unroll
            for (int ni = 0; ni < 4; ++ni)
                acc[mi][ni] = __builtin_amdgcn_mfma_f32_16x16x32_bf16(af[mi], bf[ni], acc[mi][ni], 0, 0, 0);
    }
}

// ---- BK=64 step, A direct layout, B padded-rotation layout ----
__device__ __forceinline__ void mma_step_mix(const char* As, const char* Bs,
                                             floatx4 acc[4][4], int lm, int q,
                                             int wrow, int wcol) {
    int lxor = lm & 7;
    int aoff = (wrow * 64 + lm) * 128;
    #pragma unroll
    for (int h = 0; h < 2; ++h) {
        int g = h * 4 + q;
        int sa = (g ^ lxor) << 4;
        bf16x8_t af[4], bf[4];
        #pragma unroll
        for (int i = 0; i < 4; ++i) af[i] = *(const bf16x8_t*)(As + aoff + i * 2048 + sa);
        #pragma unroll
        for (int i = 0; i < 4; ++i) {
            int brow = wcol * 64 + i * 16 + lm;
            int slot = (g + brow + (brow >> 3)) & 7;
            bf[i] = *(const bf16x8_t*)(Bs + brow * 144 + slot * 16);
        }
        #pragma unroll
        for (int mi = 0; mi < 4; ++mi)
            #pragma unroll
            for (int ni = 0; ni < 4; ++ni)
                acc[mi][ni] = __builtin_amdgcn_mfma_f32_16x16x32_bf16(af[mi], bf[ni], acc[mi][ni], 0, 0, 0);
    }
}

// ================= small / prep kernels =================

__global__ __launch_bounds__(256) void k_pool(const float* __restrict__ y,
                                              float* __restrict__ pooled) {
    int bc = blockIdx.x;
    const float* yp = y + (long)bc * HW_;
    float acc = 0.f;
    for (int n = threadIdx.x; n < HW_; n += 256) acc += yp[n];
    __shared__ float red[256];
    red[threadIdx.x] = acc;
    __syncthreads();
    for (int s = 128; s > 0; s >>= 1) {
        if (threadIdx.x < s) red[threadIdx.x] += red[threadIdx.x + s];
        __syncthreads();
    }
    if (threadIdx.x == 0) pooled[bc] = red[0] * (1.0f / HW_);
}

__global__ __launch_bounds__(128) void k_rou(const float* __restrict__ pooled,
                                             const float* __restrict__ rou_w,
                                             const float* __restrict__ rou_b,
                                             float* __restrict__ rou_y) {
    int b = blockIdx.x;
    int k = threadIdx.x;
    __shared__ float ps[C_];
    for (int c = threadIdx.x; c < C_; c += 128) ps[c] = pooled[b * C_ + c];
    __syncthreads();
    float acc = rou_b[k];
    for (int c = 0; c < C_; ++c) acc += ps[c] * rou_w[k * C_ + c];
    rou_y[b * K_ + k] = 1.0f / (1.0f + expf(-acc));
}

__global__ __launch_bounds__(256) void k_cast8(const float* __restrict__ a,
                                               __bf16* __restrict__ o) {
    long i = ((long)blockIdx.x * 256 + threadIdx.x) * 8;
    float4 v0 = *reinterpret_cast<const float4*>(a + i);
    float4 v1 = *reinterpret_cast<const float4*>(a + i + 4);
    bf16x8_t r;
    r[0] = (__bf16)v0.x; r[1] = (__bf16)v0.y; r[2] = (__bf16)v0.z; r[3] = (__bf16)v0.w;
    r[4] = (__bf16)v1.x; r[5] = (__bf16)v1.y; r[6] = (__bf16)v1.z; r[7] = (__bf16)v1.w;
    *reinterpret_cast<bf16x8_t*>(o + i) = r;
}

// ================= MFMA GEMMs =================

// phi: relu(phi_w @ X^T + b) -> phi_kn[k][n], phi_nk[n][k]; fused s[k] sums.
// B operand transposed-staged straight from xbf2 [c][n].
__global__ __launch_bounds__(256) void k_phi_m(const __bf16* __restrict__ xbf2,
                                               const __bf16* __restrict__ pwbf,
                                               const float* __restrict__ phi_b,
                                               __bf16* __restrict__ phi_kn,
                                               __bf16* __restrict__ phi_nk,
                                               float* __restrict__ sbuf) {
    int b = blockIdx.y;
    int n0 = blockIdx.x * 128;
    __shared__ __attribute__((aligned(16))) char smem[16384 + 18432];
    char* As = smem; char* Bs = smem + 16384;
    int t = threadIdx.x, w = t >> 6, lane = t & 63;
    int lm = lane & 15, q = lane >> 4;
    int wrow = w >> 1, wcol = w & 1;
    floatx4 acc[4][4];
    #pragma unroll
    for (int i = 0; i < 4; ++i)
        #pragma unroll
        for (int j = 0; j < 4; ++j) acc[i][j] = (floatx4){0.f, 0.f, 0.f, 0.f};

    const __bf16* Bb = xbf2 + (long)b * CHW;
    for (int p0 = 0; p0 < C_; p0 += 64) {
        stage128x64(pwbf, C_, 0, K_ - 1, p0, (__bf16*)As, t);
        stage_tr_phi(Bb, n0, p0, Bs, t);
        __syncthreads();
        mma_step_mix(As, Bs, acc, lm, q, wrow, wcol);
        __syncthreads();
    }
    #pragma unroll
    for (int mi = 0; mi < 4; ++mi) {
        int kb = wrow * 64 + mi * 16 + q * 4;
        float4 pb = *reinterpret_cast<const float4*>(phi_b + kb);
        float pbv[4] = {pb.x, pb.y, pb.z, pb.w};
        float sv[4] = {0.f, 0.f, 0.f, 0.f};
        #pragma unroll
        for (int ni = 0; ni < 4; ++ni) {
            int n = n0 + wcol * 64 + ni * 16 + lm;
            if (n < HW_) {
                bf16x4_t pack;
                #pragma unroll
                for (int r = 0; r < 4; ++r) {
                    float v = fmaxf(acc[mi][ni][r] + pbv[r], 0.f);
                    __bf16 vb = (__bf16)v;
                    phi_kn[((long)b * K_ + kb + r) * HW_ + n] = vb;
                    pack[r] = vb;
                    sv[r] += v;
                }
                *reinterpret_cast<bf16x4_t*>(phi_nk + ((long)b * HW_ + n) * K_ + kb) = pack;
            }
        }
        #pragma unroll
        for (int r = 0; r < 4; ++r) {
            float v = sv[r];
            v += __shfl_xor(v, 1, 64); v += __shfl_xor(v, 2, 64);
            v += __shfl_xor(v, 4, 64); v += __shfl_xor(v, 8, 64);
            if (lm == 0) atomicAdd(&sbuf[b * K_ + kb + r], v);
        }
    }
}

// fused: D[n] -> inv_s[n]; scale phi_nk row in place -> P_nk
__global__ __launch_bounds__(256) void k_d2(__bf16* __restrict__ phi_nk,
                                            const float* __restrict__ rou_y,
                                            const float* __restrict__ s,
                                            float* __restrict__ inv_s) {
    int b = blockIdx.y;
    __shared__ float ws[K_];
    int t = threadIdx.x;
    if (t < K_) ws[t] = rou_y[b * K_ + t] * s[b * K_ + t];
    __syncthreads();
    int w = t >> 6, lane = t & 63;
    int n = blockIdx.x * 4 + w;
    __bf16* p = phi_nk + ((long)b * HW_ + n) * K_ + lane * 2;
    bf16x2_t v = *reinterpret_cast<bf16x2_t*>(p);
    float f0 = (float)v[0], f1 = (float)v[1];
    float d = f0 * ws[lane * 2] + f1 * ws[lane * 2 + 1];
    #pragma unroll
    for (int off = 32; off > 0; off >>= 1) d += __shfl_xor(d, off, 64);
    float inv = rsqrtf(d + 1e-8f);
    bf16x2_t o; o[0] = (__bf16)(f0 * inv); o[1] = (__bf16)(f1 * inv);
    *reinterpret_cast<bf16x2_t*>(p) = o;
    if (lane == 0) inv_s[b * HW_ + n] = inv;
}

// t_part[nch][b][k][c] = sum_{n in chunk} phi_kn[k][n] * (x_trans[n][c]*inv_s[n])
// B transposed-staged + scaled from xbf2; no atomics. Swizzled 1D grid (448).
__global__ __launch_bounds__(256) void k_t_m(const __bf16* __restrict__ phi_kn,
                                             const __bf16* __restrict__ xbf2,
                                             const float* __restrict__ inv_s,
                                             float* __restrict__ t_part) {
    int gid = blockIdx.x;
    int rlo = gid & 7, cc4 = (gid >> 3) & 3, r8 = gid >> 5;
    int r = r8 * 8 + rlo;          // 0..111
    int b = r / 7, nch = r % 7;
    int c0 = cc4 * 128;
    __shared__ __attribute__((aligned(16))) char smem[16384 + 18432];
    char* As = smem; char* Bs = smem + 16384;
    int t = threadIdx.x, w = t >> 6, lane = t & 63;
    int lm = lane & 15, q = lane >> 4;
    int wrow = w >> 1, wcol = w & 1;
    floatx4 acc[4][4];
    #pragma unroll
    for (int i = 0; i < 4; ++i)
        #pragma unroll
        for (int j = 0; j < 4; ++j) acc[i][j] = (floatx4){0.f, 0.f, 0.f, 0.f};

    const __bf16* Ab = phi_kn + (long)b * K_ * HW_;
    const __bf16* Bb = xbf2 + (long)b * CHW;
    const float* ib = inv_s + (long)b * HW_;

    int pstart = nch * 448;
    for (int p0 = pstart; p0 < pstart + 448; p0 += 64) {
        stage128x64(Ab, HW_, 0, K_ - 1, p0, (__bf16*)As, t);
        stage_tr_t(Bb, ib, c0, p0, Bs, t);
        __syncthreads();
        mma_step_mix(As, Bs, acc, lm, q, wrow, wcol);
        __syncthreads();
    }
    float* outp = t_part + ((long)nch * B_ + b) * K_ * C_;
    #pragma unroll
    for (int mi = 0; mi < 4; ++mi) {
        int kb = wrow * 64 + mi * 16 + q * 4;
        #pragma unroll
        for (int ni = 0; ni < 4; ++ni) {
            int c = c0 + wcol * 64 + ni * 16 + lm;
            #pragma unroll
            for (int rr = 0; rr < 4; ++rr)
                outp[(long)(kb + rr) * C_ + c] = acc[mi][ni][rr];
        }
    }
}

// reduce 7 split-K partials -> t_bf (bf16)
__global__ __launch_bounds__(256) void k_tred(const float* __restrict__ t_part,
                                              __bf16* __restrict__ t_bf) {
    const long BKC = (long)B_ * K_ * C_;
    long i = ((long)blockIdx.x * 256 + threadIdx.x) * 4;
    float4 s = *reinterpret_cast<const float4*>(t_part + i);
    #pragma unroll
    for (int p = 1; p < 7; ++p) {
        float4 v = *reinterpret_cast<const float4*>(t_part + p * BKC + i);
        s.x += v.x; s.y += v.y; s.z += v.z; s.w += v.w;
    }
    bf16x4_t o;
    o[0] = (__bf16)s.x; o[1] = (__bf16)s.y; o[2] = (__bf16)s.z; o[3] = (__bf16)s.w;
    *reinterpret_cast<bf16x4_t*>(t_bf + i) = o;
}

// tzT[c][k] = -rou[k] * sum_{c'} t_bf[k][c'] * zwbf[c][c']
__global__ __launch_bounds__(256) void k_tz_m(const __bf16* __restrict__ zwbf,
                                              const __bf16* __restrict__ t_bf,
                                              const float* __restrict__ rou_y,
                                              __bf16* __restrict__ tzT) {
    int b = blockIdx.y;
    int c0 = blockIdx.x * 128;
    __shared__ __attribute__((aligned(16))) char smem[32768];
    char* As = smem; char* Bs = smem + 16384;
    int t = threadIdx.x, w = t >> 6, lane = t & 63;
    int lm = lane & 15, q = lane >> 4;
    int wrow = w >> 1, wcol = w & 1;
    floatx4 acc[4][4];
    #pragma unroll
    for (int i = 0; i < 4; ++i)
        #pragma unroll
        for (int j = 0; j < 4; ++j) acc[i][j] = (floatx4){0.f, 0.f, 0.f, 0.f};

    const __bf16* Bb = t_bf + (long)b * K_ * C_;
    int lxor = lm & 7;
    int aoff = (wrow * 64 + lm) * 128;
    int boff = (wcol * 64 + lm) * 128;

    for (int p0 = 0; p0 < C_; p0 += 64) {
        stage128x64(zwbf, C_, c0, C_ - 1, p0, (__bf16*)As, t);
        stage128x64(Bb,   C_, 0, K_ - 1, p0, (__bf16*)Bs, t);
        __syncthreads();
        mma_step64(As, Bs, acc, aoff, boff, q, lxor);
        __syncthreads();
    }
    #pragma unroll
    for (int mi = 0; mi < 4; ++mi) {
        int c = c0 + wrow * 64 + mi * 16 + q * 4;
        #pragma unroll
        for (int ni = 0; ni < 4; ++ni) {
            int k = wcol * 64 + ni * 16 + lm;
            float rk = rou_y[b * K_ + k];
            #pragma unroll
            for (int rr = 0; rr < 4; ++rr)
                tzT[((long)b * C_ + c + rr) * K_ + k] = (__bf16)(-rk * acc[mi][ni][rr]);
        }
    }
}

// out[n][c] = bf16(x) + relu( X2@zeta^T + P_nk@tzT^T + zeta_b ). Swizzled 1D grid (1600).
__global__ __launch_bounds__(256) void k_out_m(const __bf16* __restrict__ xbf2,
                                               const __bf16* __restrict__ zwbf,
                                               const __bf16* __restrict__ pnk,
                                               const __bf16* __restrict__ tzT,
                                               const float* __restrict__ zeta_b,
                                               float* __restrict__ out) {
    int gid = blockIdx.x;
    int rlo = gid & 7, cc4 = (gid >> 3) & 3, r8 = gid >> 5;
    int r = r8 * 8 + rlo;          // 0..399
    int b = r / 25, nt = r % 25;
    int n0 = nt * 128;
    int c0 = cc4 * 128;
    __shared__ __attribute__((aligned(16))) char smem[32768];
    char* As = smem; char* Bs = smem + 16384;
    int t = threadIdx.x, w = t >> 6, lane = t & 63;
    int lm = lane & 15, q = lane >> 4;
    int wrow = w >> 1, wcol = w & 1;
    floatx4 acc[4][4];
    #pragma unroll
    for (int i = 0; i < 4; ++i)
        #pragma unroll
        for (int j = 0; j < 4; ++j) acc[i][j] = (floatx4){0.f, 0.f, 0.f, 0.f};

    int lxor = lm & 7;
    int aoff = (wrow * 64 + lm) * 128;
    int boff = (wcol * 64 + lm) * 128;

    // phase 1: X2 @ zeta^T  (red = 512)
    const __bf16* A1 = xbf2 + (long)b * CHW;
    for (int p0 = 0; p0 < C_; p0 += 64) {
        stage128x64(A1,   C_, n0, HW_ - 1, p0, (__bf16*)As, t);
        stage128x64(zwbf, C_, c0, C_ - 1, p0, (__bf16*)Bs, t);
        __syncthreads();
        mma_step64(As, Bs, acc, aoff, boff, q, lxor);
        __syncthreads();
    }
    // phase 2: P_nk @ tzT^T  (red = 128, tzT pre-negated & rou-folded)
    const __bf16* A2 = pnk + (long)b * (long)HW_ * K_;
    const __bf16* B2 = tzT + (long)b * (long)C_ * K_;
    for (int p0 = 0; p0 < K_; p0 += 64) {
        stage128x64(A2, K_, n0, HW_ - 1, p0, (__bf16*)As, t);
        stage128x64(B2, K_, c0, C_ - 1, p0, (__bf16*)Bs, t);
        __syncthreads();
        mma_step64(As, Bs, acc, aoff, boff, q, lxor);
        __syncthreads();
    }
    // epilogue: LDS bounce, coalesced dwordx4 stores
    float* ep = (float*)smem;                   // [32][132]
    const __bf16* xres = xbf2 + (long)b * CHW;
    int lr = t >> 3, lc = (t & 7) * 16;
    #pragma unroll
    for (int ch = 0; ch < 4; ++ch) {
        __syncthreads();
        if (wrow == (ch >> 1)) {
            #pragma unroll
            for (int mm = 0; mm < 2; ++mm) {
                int mi = (ch & 1) * 2 + mm;
                #pragma unroll
                for (int ni = 0; ni < 4; ++ni)
                    #pragma unroll
                    for (int rr = 0; rr < 4; ++rr)
                        ep[(mm * 16 + q * 4 + rr) * 132 + wcol * 64 + ni * 16 + lm] = acc[mi][ni][rr];
            }
        }
        __syncthreads();
        int n = n0 + ch * 32 + lr;
        if (n < HW_) {
            long rowbase = (long)n * C_ + c0 + lc;
            bf16x8_t x0 = *(const bf16x8_t*)(xres + rowbase);
            bf16x8_t x1 = *(const bf16x8_t*)(xres + rowbase + 8);
            float xv[16];
            #pragma unroll
            for (int j = 0; j < 8; ++j) { xv[j] = (float)x0[j]; xv[8 + j] = (float)x1[j]; }
            float* orow = out + (long)b * CHW + rowbase;
            #pragma unroll
            for (int jj = 0; jj < 4; ++jj) {
                float4 zb = *reinterpret_cast<const float4*>(zeta_b + c0 + lc + jj * 4);
                float4 e  = *reinterpret_cast<const float4*>(&ep[lr * 132 + lc + jj * 4]);
                float4 o;
                o.x = xv[jj * 4 + 0] + fmaxf(e.x + zb.x, 0.f);
                o.y = xv[jj * 4 + 1] + fmaxf(e.y + zb.y, 0.f);
                o.z = xv[jj * 4 + 2] + fmaxf(e.z + zb.z, 0.f);
                o.w = xv[jj * 4 + 3] + fmaxf(e.w + zb.w, 0.f);
                *reinterpret_cast<float4*>(orow + jj * 4) = o;
            }
        }
    }
}

extern "C" void kernel_launch(void* const* d_in, const int* in_sizes, int n_in,
                              void* d_out, int out_size, void* d_ws, size_t ws_size,
                              hipStream_t stream) {
    const float* x      = (const float*)d_in[0];
    const float* y      = (const float*)d_in[1];
    const float* phi_w  = (const float*)d_in[2];
    const float* phi_b  = (const float*)d_in[3];
    const float* rou_w  = (const float*)d_in[4];
    const float* rou_b  = (const float*)d_in[5];
    const float* zeta_w = (const float*)d_in[6];
    const float* zeta_b = (const float*)d_in[7];
    float* out = (float*)d_out;

    char* p = (char*)d_ws;
    __bf16* xbf2   = (__bf16*)p; p += (size_t)B_ * CHW * 2;              // 51.4 MB
    __bf16* phi_kn = (__bf16*)p; p += (size_t)B_ * K_ * HW_ * 2;         // 12.85 MB
    __bf16* phi_nk = (__bf16*)p; p += (size_t)B_ * K_ * HW_ * 2;         // 12.85 MB (-> P_nk)
    float*  t_part = (float*) p; p += (size_t)7 * B_ * K_ * C_ * 4;      // 29.4 MB
    __bf16* t_bf   = (__bf16*)p; p += (size_t)B_ * K_ * C_ * 2;          // 2.1 MB
    __bf16* tzT    = (__bf16*)p; p += (size_t)B_ * C_ * K_ * 2;          // 2.1 MB
    __bf16* pwbf   = (__bf16*)p; p += (size_t)K_ * C_ * 2;
    __bf16* zwbf   = (__bf16*)p; p += (size_t)C_ * C_ * 2;
    float*  pooled = (float*) p; p += (size_t)B_ * C_ * 4;
    float*  rou_y  = (float*) p; p += (size_t)B_ * K_ * 4;
    float*  sbuf   = (float*) p; p += (size_t)B_ * K_ * 4;
    float*  inv_s  = (float*) p; p += (size_t)B_ * HW_ * 4;

    hipMemsetAsync(sbuf, 0, B_ * K_ * sizeof(float), stream);

    k_pool <<<B_ * C_, 256, 0, stream>>>(y, pooled);
    k_rou  <<<B_, 128, 0, stream>>>(pooled, rou_w, rou_b, rou_y);
    k_cast8<<<(K_ * C_) / 2048, 256, 0, stream>>>(phi_w, pwbf);
    k_cast8<<<(C_ * C_) / 2048, 256, 0, stream>>>(zeta_w, zwbf);
    k_cast8<<<(B_ * (long)CHW) / 2048, 256, 0, stream>>>(x, xbf2);
    k_phi_m<<<dim3(25, B_), 256, 0, stream>>>(xbf2, pwbf, phi_b, phi_kn, phi_nk, sbuf);
    k_d2   <<<dim3(HW_ / 4, B_), 256, 0, stream>>>(phi_nk, rou_y, sbuf, inv_s);
    k_t_m  <<<448, 256, 0, stream>>>(phi_kn, xbf2, inv_s, t_part);
    k_tred <<<(B_ * K_ * C_) / 1024, 256, 0, stream>>>(t_part, t_bf);
    k_tz_m <<<dim3(C_ / 128, B_), 256, 0, stream>>>(zwbf, t_bf, rou_y, tzT);
    k_out_m<<<1600, 256, 0, stream>>>(xbf2, zwbf, phi_nk, tzT, zeta_b, out);
}